// Round 1
// baseline (880.864 us; speedup 1.0000x reference)
//
#include <hip/hip_runtime.h>
#include <hip/hip_bf16.h>

#define NMAT 1000        // timesteps
#define SA_PAD 68        // fp32 LDS row stride for 64x64 matmul tiles (float4-aligned, conflict-light)
#define LDM 72           // bf16 LDS row stride for MFMA operand tiles (16B-aligned octets, 2-way max conflict)

typedef short short8 __attribute__((ext_vector_type(8)));    // 8 x bf16 payload for MFMA operands
typedef float floatx4 __attribute__((ext_vector_type(4)));   // MFMA accumulator

__device__ inline unsigned short f2bf(float f) {
    // fp32 -> bf16 round-to-nearest-even
    unsigned int u = __float_as_uint(f);
    u += 0x7fffu + ((u >> 16) & 1u);
    return (unsigned short)(u >> 16);
}

// In-block 64x64x64 fp32 matmul: C = A*B, optional epilogue C += cI*I + c1*E1 + c2*E2 + c3*E3.
// 256 threads, each computes a 4x4 tile. sA/sB are shared buffers with row stride SA_PAD.
__device__ void mm64(float* __restrict__ C, const float* __restrict__ A,
                     const float* __restrict__ B,
                     const float* E1, const float* E2, const float* E3,
                     float cI, float c1, float c2, float c3, int doEpi,
                     float* sA, float* sB)
{
    const int tid = threadIdx.x;
#pragma unroll
    for (int s = 0; s < 16; ++s) {
        int idx = tid + 256 * s;
        int r = idx >> 6, c = idx & 63;
        sA[r * SA_PAD + c] = A[idx];
        sB[r * SA_PAD + c] = B[idx];
    }
    __syncthreads();

    const int r0 = (tid >> 4) * 4, c0 = (tid & 15) * 4;
    float acc[4][4] = {};
    for (int k = 0; k < 64; k += 4) {
        float4 b0 = *(const float4*)&sB[(k + 0) * SA_PAD + c0];
        float4 b1 = *(const float4*)&sB[(k + 1) * SA_PAD + c0];
        float4 b2 = *(const float4*)&sB[(k + 2) * SA_PAD + c0];
        float4 b3 = *(const float4*)&sB[(k + 3) * SA_PAD + c0];
#pragma unroll
        for (int u = 0; u < 4; ++u) {
            float4 a = *(const float4*)&sA[(r0 + u) * SA_PAD + k];
            acc[u][0] += a.x * b0.x + a.y * b1.x + a.z * b2.x + a.w * b3.x;
            acc[u][1] += a.x * b0.y + a.y * b1.y + a.z * b2.y + a.w * b3.y;
            acc[u][2] += a.x * b0.z + a.y * b1.z + a.z * b2.z + a.w * b3.z;
            acc[u][3] += a.x * b0.w + a.y * b1.w + a.z * b2.w + a.w * b3.w;
        }
    }
#pragma unroll
    for (int u = 0; u < 4; ++u) {
#pragma unroll
        for (int v = 0; v < 4; ++v) {
            int r = r0 + u, c = c0 + v;
            float val = acc[u][v];
            if (doEpi) {
                val += (r == c ? cI : 0.f) + c1 * E1[r * 64 + c]
                     + c2 * E2[r * 64 + c] + c3 * E3[r * 64 + c];
            }
            C[r * 64 + c] = val;
        }
    }
    __syncthreads();   // global C visible block-wide; LDS reusable by next call
}

// Kernel 1: M = expm(K) via degree-12 Taylor (Paterson-Stockmeyer s=4), then seed M^2..M^4.
// tab layout in ws: tab[i] = M^i at ws + i*4096 (fp32), i = 0..999. Temps after the table.
__global__ __launch_bounds__(256) void k_expm(const float* __restrict__ K, float* __restrict__ ws)
{
    __shared__ __align__(16) float sA[64 * SA_PAD];
    __shared__ __align__(16) float sB[64 * SA_PAD];
    float* tab = ws;
    float* T2 = ws + (size_t)NMAT * 4096;
    float* T3 = T2 + 4096;
    float* T4 = T3 + 4096;
    float* P1 = T4 + 4096;
    float* P2 = P1 + 4096;

    const float c1_ = 1.f, c2_ = 0.5f, c3_ = 1.f / 6.f, c4_ = 1.f / 24.f, c5_ = 1.f / 120.f,
                c6_ = 1.f / 720.f, c7_ = 1.f / 5040.f, c8_ = 1.f / 40320.f, c9_ = 1.f / 362880.f,
                c10_ = 1.f / 3628800.f, c11_ = 1.f / 39916800.f, c12_ = 1.f / 479001600.f;

    mm64(T2, K, K, K, K, K, 0, 0, 0, 0, 0, sA, sB);     // K^2
    mm64(T3, T2, K, K, K, K, 0, 0, 0, 0, 0, sA, sB);    // K^3
    mm64(T4, T2, T2, K, K, K, 0, 0, 0, 0, 0, sA, sB);   // K^4

    const int tid = threadIdx.x;
    // P1 = c12*T4 + (c8*I + c9*K + c10*T2 + c11*T3)   [B3*T4 + B2, B3 = c12*I]
#pragma unroll
    for (int s = 0; s < 16; ++s) {
        int idx = tid + 256 * s;
        int r = idx >> 6, c = idx & 63;
        P1[idx] = c12_ * T4[idx] + (r == c ? c8_ : 0.f) + c9_ * K[idx] + c10_ * T2[idx] + c11_ * T3[idx];
    }
    __syncthreads();

    mm64(P2, P1, T4, K, T2, T3, c4_, c5_, c6_, c7_, 1, sA, sB);            // + B1
    mm64(tab + 1 * 4096, P2, T4, K, T2, T3, 1.f, c1_, c2_, c3_, 1, sA, sB); // M = P2*T4 + B0

    // tab[0] = I
#pragma unroll
    for (int s = 0; s < 16; ++s) {
        int idx = tid + 256 * s;
        int r = idx >> 6, c = idx & 63;
        tab[idx] = (r == c) ? 1.f : 0.f;
    }
    __syncthreads();

    mm64(tab + 2 * 4096, tab + 1 * 4096, tab + 1 * 4096, K, K, K, 0, 0, 0, 0, 0, sA, sB); // M^2
    mm64(tab + 3 * 4096, tab + 2 * 4096, tab + 1 * 4096, K, K, K, 0, 0, 0, 0, 0, sA, sB); // M^3
    mm64(tab + 4 * 4096, tab + 2 * 4096, tab + 2 * 4096, K, K, K, 0, 0, 0, 0, 0, sA, sB); // M^4
}

// Kernel 2: one doubling round. Block j computes tab[firstDst+j] = tab[aIdx] * tab[firstDst+j-aIdx].
__global__ __launch_bounds__(256) void k_round(float* __restrict__ ws, int aIdx, int firstDst)
{
    __shared__ __align__(16) float sA[64 * SA_PAD];
    __shared__ __align__(16) float sB[64 * SA_PAD];
    float* tab = ws;
    int dst = firstDst + blockIdx.x;
    mm64(tab + (size_t)dst * 4096, tab + (size_t)aIdx * 4096,
         tab + (size_t)(dst - aIdx) * 4096, tab, tab, tab, 0, 0, 0, 0, 0, sA, sB);
}

// Kernel 3: y[b,t,:] = M^t * x0[b]. Block = (t, 128-row b-tile). bf16 MFMA 16x16x32, fp32 accum.
__global__ __launch_bounds__(256) void k_out(const float* __restrict__ in,
                                             const float* __restrict__ ws,
                                             float* __restrict__ out)
{
    __shared__ __align__(16) unsigned short lM[64 * LDM];    // M_t, row-major [i][j], bf16
    __shared__ __align__(16) unsigned short lX[128 * LDM];   // x0 tile,  [b_local][j], bf16

    const int bx = blockIdx.x;
    const int t = bx >> 3;
    const int b0 = (bx & 7) * 128;
    const float* Mt = ws + (size_t)t * 4096;
    const int tid = threadIdx.x;

    // stage M_t (fp32 -> bf16)
#pragma unroll
    for (int s = 0; s < 16; ++s) {
        int idx = tid + 256 * s;
        int i = idx >> 6, j = idx & 63;
        lM[i * LDM + j] = f2bf(Mt[idx]);
    }
    // stage x0 tile: x0[b][j] = in[b*64000 + j]  (t=0 slice)
#pragma unroll
    for (int s = 0; s < 32; ++s) {
        int idx = tid + 256 * s;     // 8192 elements
        int bb = idx >> 6, j = idx & 63;
        lX[bb * LDM + j] = f2bf(in[(size_t)(b0 + bb) * 64000 + j]);
    }
    __syncthreads();

    const int lane = tid & 63;
    const int w = tid >> 6;         // wave id 0..3
    const int m = lane & 15;        // A/B fragment row index within 16
    const int kg = lane >> 4;       // k-octet group 0..3 (also C/D row quad)

#pragma unroll
    for (int mt = 0; mt < 2; ++mt) {
        const int mtile = w * 2 + mt;    // 0..7 -> b rows [mtile*16, +16)
        short8 a0 = *(const short8*)&lX[(mtile * 16 + m) * LDM + kg * 8];        // k 0..31
        short8 a1 = *(const short8*)&lX[(mtile * 16 + m) * LDM + 32 + kg * 8];   // k 32..63
#pragma unroll
        for (int n = 0; n < 4; ++n) {    // output i-tile
            short8 bf0 = *(const short8*)&lM[(n * 16 + m) * LDM + kg * 8];
            short8 bf1 = *(const short8*)&lM[(n * 16 + m) * LDM + 32 + kg * 8];
            floatx4 acc = {0.f, 0.f, 0.f, 0.f};
            acc = __builtin_amdgcn_mfma_f32_16x16x32_bf16(a0, bf0, acc, 0, 0, 0);
            acc = __builtin_amdgcn_mfma_f32_16x16x32_bf16(a1, bf1, acc, 0, 0, 0);
            // C/D layout: col = lane&15 (= i within tile), row = kg*4 + v (= b within mtile)
            size_t base = (size_t)(b0 + mtile * 16 + kg * 4) * 64000 + (size_t)t * 64 + n * 16 + m;
            out[base + 0 * 64000] = acc[0];
            out[base + 1 * 64000] = acc[1];
            out[base + 2 * 64000] = acc[2];
            out[base + 3 * 64000] = acc[3];
        }
    }
}

extern "C" void kernel_launch(void* const* d_in, const int* in_sizes, int n_in,
                              void* d_out, int out_size, void* d_ws, size_t ws_size,
                              hipStream_t stream)
{
    const float* inp = (const float*)d_in[0];   // (1024, 1000, 64) fp32
    const float* K   = (const float*)d_in[1];   // (64, 64) fp32
    float* out = (float*)d_out;                 // (1024, 1000, 64) fp32
    float* ws  = (float*)d_ws;                  // needs (1000+5)*4096*4 B ~= 16.5 MB

    hipLaunchKernelGGL(k_expm, dim3(1), dim3(256), 0, stream, K, ws);

    // Doubling rounds: known power set {0..N-1} -> {0..2N-2}; N: 5,9,17,33,65,129,257,513,1000
    const int a[8]     = {4, 8, 16, 32, 64, 128, 256, 512};
    const int first[8] = {5, 9, 17, 33, 65, 129, 257, 513};
    const int cnt[8]   = {4, 8, 16, 32, 64, 128, 256, 487};
    for (int r = 0; r < 8; ++r) {
        hipLaunchKernelGGL(k_round, dim3(cnt[r]), dim3(256), 0, stream, ws, a[r], first[r]);
    }

    hipLaunchKernelGGL(k_out, dim3(8000), dim3(256), 0, stream, inp, ws, out);
}